// Round 5
// baseline (583.826 us; speedup 1.0000x reference)
//
#include <hip/hip_runtime.h>
#include <math.h>

// Problem constants
#define N_NODES 50000
#define N_EDGES 800000
#define IN_CH 128
#define HID 256
#define OUT_CH 40

typedef unsigned short u16;
typedef __attribute__((ext_vector_type(8))) short bf16x8;
typedef __attribute__((ext_vector_type(4))) float f32x4;

__device__ __forceinline__ float bf2f(u16 u) {
    union { unsigned int i; float f; } v; v.i = ((unsigned int)u) << 16; return v.f;
}
__device__ __forceinline__ u16 f2bf(float f) {   // round-to-nearest-even
    union { float f; unsigned int i; } v; v.f = f;
    unsigned int x = v.i;
    x += 0x7fffu + ((x >> 16) & 1u);
    return (u16)(x >> 16);
}

#define GLOBAL_AS __attribute__((address_space(1)))
#define LDS_AS __attribute__((address_space(3)))
__device__ __forceinline__ void async_cp16(const void* g, void* l) {
    __builtin_amdgcn_global_load_lds((const GLOBAL_AS unsigned int*)g,
                                     (LDS_AS unsigned int*)l, 16, 0, 0);
}

// ===========================================================================
// Fused prep: degree histogram + x->bf16 conversion + 5 weight transposes.
// All independent; the latency-bound atomic histogram hides the streaming
// conversions. Block ranges:
//   [0,3125)        deg_count   (800k edges / 256)
//   [3125,9375)     conv_x_bf   (1.6M float4 / 256)
//   [9375,10527)    transposes  (1152 output rows)
// ===========================================================================
__device__ __forceinline__ void tr_one(
    const float* __restrict__ in, u16* __restrict__ out, int K, int N, int n)
{
    for (int k = threadIdx.x; k < K; k += 256) {
        float v = (n < N) ? in[(size_t)k * N + n] : 0.f;
        out[(size_t)n * K + k] = f2bf(v);
    }
}

__global__ __launch_bounds__(256) void prep_fused(
    const int* __restrict__ ei, int* __restrict__ deg,
    const float* __restrict__ x, u16* __restrict__ xb,
    const float* __restrict__ W1a, const float* __restrict__ W2a,
    const float* __restrict__ W1b, const float* __restrict__ W2b,
    const float* __restrict__ Wlin,
    u16* __restrict__ W1aT, u16* __restrict__ W2aT,
    u16* __restrict__ W1bT, u16* __restrict__ W2bT, u16* __restrict__ WlinT)
{
    int b = blockIdx.x;
    if (b < 3125) {
        int e = b * 256 + threadIdx.x;
        if (e < N_EDGES) atomicAdd(&deg[ei[N_EDGES + e]], 1);
    } else if (b < 9375) {
        int i = (b - 3125) * 256 + threadIdx.x;
        float4 v = ((const float4*)x)[i];
        ushort4 o;
        o.x = f2bf(v.x); o.y = f2bf(v.y); o.z = f2bf(v.z); o.w = f2bf(v.w);
        ((ushort4*)xb)[i] = o;
    } else {
        int t = b - 9375;
        if (t < 256)       tr_one(W1a, W1aT, IN_CH, HID, t);
        else if (t < 512)  tr_one(W2a, W2aT, HID, HID, t - 256);
        else if (t < 768)  tr_one(W1b, W1bT, HID, HID, t - 512);
        else if (t < 1024) tr_one(W2b, W2bT, HID, HID, t - 768);
        else               tr_one(Wlin, WlinT, 2 * HID, OUT_CH, t - 1024);
    }
}

// ===========================================================================
// Scan (3 small kernels) + CSR fill (u16 src ids)
// ===========================================================================
__global__ __launch_bounds__(256) void scan1(
    const int* __restrict__ deg, int* __restrict__ excl, int* __restrict__ partials)
{
    __shared__ int lds[256];
    const int tid = threadIdx.x;
    const int base = blockIdx.x * 1024 + tid * 4;
    int v[4]; int s = 0;
#pragma unroll
    for (int i = 0; i < 4; i++) {
        int idx = base + i;
        v[i] = (idx < N_NODES) ? deg[idx] : 0;
        s += v[i];
    }
    lds[tid] = s;
    __syncthreads();
    for (int off = 1; off < 256; off <<= 1) {
        int t = (tid >= off) ? lds[tid - off] : 0;
        __syncthreads();
        lds[tid] += t;
        __syncthreads();
    }
    int run = lds[tid] - s;
#pragma unroll
    for (int i = 0; i < 4; i++) {
        int idx = base + i;
        if (idx < N_NODES) excl[idx] = run;
        run += v[i];
    }
    if (tid == 255) partials[blockIdx.x] = lds[255];
}

__global__ __launch_bounds__(64) void scan2(int* __restrict__ partials, int n)
{
    int l = threadIdx.x;
    int orig = (l < n) ? partials[l] : 0;
    int v = orig;
#pragma unroll
    for (int off = 1; off < 64; off <<= 1) {
        int t = __shfl_up(v, off, 64);
        if (l >= off) v += t;
    }
    if (l < n) partials[l] = v - orig;
}

__global__ __launch_bounds__(256) void scan3(
    int* __restrict__ excl, const int* __restrict__ partials, int* __restrict__ cursor)
{
    int idx = blockIdx.x * 256 + threadIdx.x;
    if (idx < N_NODES) {
        int r = excl[idx] + partials[idx >> 10];
        excl[idx] = r;
        cursor[idx] = r;
    }
}

__global__ __launch_bounds__(256) void csr_fill(
    const int* __restrict__ ei, int* __restrict__ cursor, u16* __restrict__ csr_src)
{
    int e = blockIdx.x * 256 + threadIdx.x;
    if (e < N_EDGES) {
        int s = ei[e];
        int d = ei[N_EDGES + e];
        int pos = atomicAdd(&cursor[d], 1);
        csr_src[pos] = (u16)s;
    }
}

// ===========================================================================
// XCD-sharded gather aggregation (bf16 in/out, fp32 accumulate):
//   out[n][c] = feat[n][c] + sum_{e in row n} feat[src[e]][c]
// Channel slice of 32 ch (64 B) pinned to an XCD via blockIdx%8, so each
// XCD's 4 MiB L2 holds its whole slice (3.2 MB) -> gathers hit L2, not LLC.
// One wave per (node, slice): 4 groups x 16 lanes, group g walks edges
// j = start+g, start+g+4, ... (4 rows in flight); cross-group shuffle reduce.
// 256ch: 8 slices (grid 8*12500); 128ch: 4 slices (grid 4*12500, 2 XCDs/slice).
// ===========================================================================
template <int C, int NSLICE>
__global__ __launch_bounds__(256) void gather_shard(
    const u16* __restrict__ feat, const int* __restrict__ row_ptr,
    const int* __restrict__ row_end, const u16* __restrict__ csr_src,
    u16* __restrict__ out)
{
    const int b = blockIdx.x;
    const int slice = b & (NSLICE - 1);
    const int chunk = b >> (NSLICE == 8 ? 3 : 2);
    const int wid = threadIdx.x >> 6;
    const int node = chunk * 4 + wid;
    const int lane = threadIdx.x & 63;
    const int g = lane >> 4, li = lane & 15;
    const int coff = slice * 32 + li * 2;

    float ax = 0.f, ay = 0.f;
    if (g == 0) {
        ushort2 sv = *(const ushort2*)(feat + (size_t)node * C + coff);
        ax = bf2f(sv.x); ay = bf2f(sv.y);
    }
    const int e = row_end[node];
    for (int j = row_ptr[node] + g; j < e; j += 4) {
        int src = csr_src[j];
        ushort2 v = *(const ushort2*)(feat + (size_t)src * C + coff);
        ax += bf2f(v.x); ay += bf2f(v.y);
    }
    ax += __shfl_xor(ax, 16, 64); ax += __shfl_xor(ax, 32, 64);
    ay += __shfl_xor(ay, 16, 64); ay += __shfl_xor(ay, 32, 64);
    if (g == 0) {
        ushort2 o; o.x = f2bf(ax); o.y = f2bf(ay);
        *(ushort2*)(out + (size_t)node * C + coff) = o;
    }
}

// ===========================================================================
// bf16 MFMA GEMM (m97 structure): out = act(Aeff[M,K] @ BT^T + bias)
// (unchanged from R4; see comments there)
// ===========================================================================
__global__ __launch_bounds__(256, 2) void gemm_mfma(
    const u16* __restrict__ A, const u16* __restrict__ Acat, int Ksplit, int ldA,
    const u16* __restrict__ BT, const float* __restrict__ bias,
    void* __restrict__ out, int M, int Nreal, int K, int relu, int ldOut,
    int fuseLS)
{
    __shared__ u16 As[128 * 32];
    __shared__ u16 Bs[128 * 32];

    const int tid = threadIdx.x;
    const int lane = tid & 63;
    const int wid = tid >> 6;
    const int wm = wid >> 1, wn = wid & 1;
    const int row0 = blockIdx.y * 128;
    const int col0 = blockIdx.x * 128;

    f32x4 acc[4][4];
#pragma unroll
    for (int i = 0; i < 4; i++)
#pragma unroll
        for (int j = 0; j < 4; j++) acc[i][j] = (f32x4){0.f, 0.f, 0.f, 0.f};

    for (int kk = 0; kk < K; kk += 32) {
        const u16* Abase = (Acat != nullptr && kk >= Ksplit) ? Acat : A;
        const int kbase = (Acat != nullptr && kk >= Ksplit) ? (kk - Ksplit) : kk;
#pragma unroll
        for (int i = 0; i < 2; i++) {
            int chunk = i * 256 + tid;
            int r = chunk >> 2, c = chunk & 3;
            int grow = row0 + r; if (grow > M - 1) grow = M - 1;
            async_cp16(Abase + (size_t)grow * ldA + kbase + c * 8, As + chunk * 8);
        }
#pragma unroll
        for (int i = 0; i < 2; i++) {
            int chunk = i * 256 + tid;
            int r = chunk >> 2, c = chunk & 3;
            async_cp16(BT + (size_t)(col0 + r) * K + kk + c * 8, Bs + chunk * 8);
        }
        __syncthreads();

        const int koff = (lane >> 4) * 8;
        const int am = wm * 64 + (lane & 15);
        const int bn = wn * 64 + (lane & 15);
        bf16x8 af[4], bfr[4];
#pragma unroll
        for (int t = 0; t < 4; t++) {
            af[t]  = *(const bf16x8*)(As + (am + t * 16) * 32 + koff);
            bfr[t] = *(const bf16x8*)(Bs + (bn + t * 16) * 32 + koff);
        }
#pragma unroll
        for (int mt = 0; mt < 4; mt++)
#pragma unroll
            for (int nt = 0; nt < 4; nt++)
                acc[mt][nt] = __builtin_amdgcn_mfma_f32_16x16x32_bf16(
                    af[mt], bfr[nt], acc[mt][nt], 0, 0, 0);
        __syncthreads();
    }

    if (fuseLS) {
        if (wn != 0) return;
        const int quad = lane >> 4, li = lane & 15;
        float b0 = bias[li];
        float b1 = bias[16 + li];
        float b2 = (li < 8) ? bias[32 + li] : 0.f;
        float* o = (float*)out;
#pragma unroll
        for (int mt = 0; mt < 4; mt++) {
#pragma unroll
            for (int reg = 0; reg < 4; reg++) {
                int row = row0 + wm * 64 + mt * 16 + quad * 4 + reg;
                float v0 = acc[mt][0][reg] + b0;
                float v1 = acc[mt][1][reg] + b1;
                float v2 = (li < 8) ? (acc[mt][2][reg] + b2) : -INFINITY;
                float m = fmaxf(fmaxf(v0, v1), v2);
#pragma unroll
                for (int off = 1; off < 16; off <<= 1)
                    m = fmaxf(m, __shfl_xor(m, off, 64));
                float s = expf(v0 - m) + expf(v1 - m)
                        + ((li < 8) ? expf(v2 - m) : 0.f);
#pragma unroll
                for (int off = 1; off < 16; off <<= 1)
                    s += __shfl_xor(s, off, 64);
                float lg = m + logf(s);
                if (row < M) {
                    o[(size_t)row * OUT_CH + li] = v0 - lg;
                    o[(size_t)row * OUT_CH + 16 + li] = v1 - lg;
                    if (li < 8) o[(size_t)row * OUT_CH + 32 + li] = v2 - lg;
                }
            }
        }
        return;
    }

#pragma unroll
    for (int nt = 0; nt < 4; nt++) {
        int col = col0 + wn * 64 + nt * 16 + (lane & 15);
        bool colOk = (col < Nreal);
        float bv = colOk ? bias[col] : 0.f;
#pragma unroll
        for (int mt = 0; mt < 4; mt++) {
            int rbase = row0 + wm * 64 + mt * 16 + ((lane >> 4) << 2);
#pragma unroll
            for (int reg = 0; reg < 4; reg++) {
                int row = rbase + reg;
                if (colOk && row < M) {
                    float v = acc[mt][nt][reg] + bv;
                    if (relu) v = fmaxf(v, 0.f);
                    ((u16*)out)[(size_t)row * ldOut + col] = f2bf(v);
                }
            }
        }
    }
}

// ---------------------------------------------------------------------------
extern "C" void kernel_launch(void* const* d_in, const int* in_sizes, int n_in,
                              void* d_out, int out_size, void* d_ws, size_t ws_size,
                              hipStream_t stream)
{
    const float* x    = (const float*)d_in[0];
    const int*   ei   = (const int*)d_in[1];
    const float* W1a  = (const float*)d_in[2];
    const float* b1a  = (const float*)d_in[3];
    const float* W2a  = (const float*)d_in[4];
    const float* b2a  = (const float*)d_in[5];
    const float* W1b  = (const float*)d_in[6];
    const float* b1b  = (const float*)d_in[7];
    const float* W2b  = (const float*)d_in[8];
    const float* b2b  = (const float*)d_in[9];
    const float* Wlin = (const float*)d_in[10];
    const float* blin = (const float*)d_in[11];
    float* out = (float*)d_out;

    // ---- workspace carve-up (regions of 50000*256 bf16 = 25.6 MB) ----
    const size_t R = (size_t)N_NODES * HID;
    u16* R0 = (u16*)d_ws;          // xbf -> t2
    u16* R1 = R0 + R;              // zA
    u16* R2 = R1 + R;              // t1 -> h2
    u16* R3 = R2 + R;              // h1 (live to end)
    u16* R4 = R3 + R;              // zB
    u16* xbf = R0;
    u16* zA  = R1;
    u16* t1  = R2;
    u16* h1  = R3;
    u16* zB  = R4;
    u16* t2  = R0;
    u16* h2  = R2;

    u16* wts = R4 + R;
    u16* W1aT = wts;                       // [256,128]
    u16* W2aT = W1aT + 256 * 128;          // [256,256]
    u16* W1bT = W2aT + 256 * 256;
    u16* W2bT = W1bT + 256 * 256;
    u16* WlinT = W2bT + 256 * 256;         // [128,512] (rows 40..127 zero)
    int* deg    = (int*)(WlinT + 128 * 512);
    int* rowp   = deg + N_NODES;
    int* cursor = rowp + N_NODES;
    int* part   = cursor + N_NODES;
    u16* csr    = (u16*)(part + 64);       // [N_EDGES] u16 src ids

    dim3 blk(256);
    const int scanBlocks = (N_NODES + 1023) / 1024;  // 49
    const int edgeBlocks = (N_EDGES + 255) / 256;
    dim3 g2(2, (N_NODES + 127) / 128);
    dim3 g1(1, (N_NODES + 127) / 128);

    // ---- prep: histogram + conversions (fused) ----
    hipMemsetAsync(deg, 0, N_NODES * sizeof(int), stream);
    prep_fused<<<10527, blk, 0, stream>>>(ei, deg, x, xbf,
                                          W1a, W2a, W1b, W2b, Wlin,
                                          W1aT, W2aT, W1bT, W2bT, WlinT);
    scan1<<<scanBlocks, blk, 0, stream>>>(deg, rowp, part);
    scan2<<<1, 64, 0, stream>>>(part, scanBlocks);
    scan3<<<(N_NODES + 255) / 256, blk, 0, stream>>>(rowp, part, cursor);
    csr_fill<<<edgeBlocks, blk, 0, stream>>>(ei, cursor, csr);

    // ---- Layer a ----
    gather_shard<IN_CH, 4><<<4 * (N_NODES / 4), blk, 0, stream>>>(
        xbf, rowp, cursor, csr, zA);
    gemm_mfma<<<g2, blk, 0, stream>>>(zA, nullptr, 0, IN_CH, W1aT, b1a,
                                      t1, N_NODES, HID, IN_CH, 1, HID, 0);
    gemm_mfma<<<g2, blk, 0, stream>>>(t1, nullptr, 0, HID, W2aT, b2a,
                                      h1, N_NODES, HID, HID, 1, HID, 0);

    // ---- Layer b ----
    gather_shard<HID, 8><<<8 * (N_NODES / 4), blk, 0, stream>>>(
        h1, rowp, cursor, csr, zB);
    gemm_mfma<<<g2, blk, 0, stream>>>(zB, nullptr, 0, HID, W1bT, b1b,
                                      t2, N_NODES, HID, HID, 1, HID, 0);
    gemm_mfma<<<g2, blk, 0, stream>>>(t2, nullptr, 0, HID, W2bT, b2b,
                                      h2, N_NODES, HID, HID, 1, HID, 0);

    // ---- Final linear on [h1 | h2] + fused log_softmax -> d_out ----
    gemm_mfma<<<g1, blk, 0, stream>>>(h1, h2, HID, HID, WlinT, blin,
                                      out, N_NODES, OUT_CH, 2 * HID, 0, OUT_CH, 1);
}

// Round 6
// 414.487 us; speedup vs baseline: 1.4086x; 1.4086x over previous
//
#include <hip/hip_runtime.h>
#include <math.h>

// Problem constants
#define N_NODES 50000
#define N_EDGES 800000
#define IN_CH 128
#define HID 256
#define OUT_CH 40

typedef unsigned short u16;
typedef __attribute__((ext_vector_type(8))) short bf16x8;
typedef __attribute__((ext_vector_type(4))) float f32x4;

__device__ __forceinline__ float bf2f(u16 u) {
    union { unsigned int i; float f; } v; v.i = ((unsigned int)u) << 16; return v.f;
}
__device__ __forceinline__ u16 f2bf(float f) {   // round-to-nearest-even
    union { float f; unsigned int i; } v; v.f = f;
    unsigned int x = v.i;
    x += 0x7fffu + ((x >> 16) & 1u);
    return (u16)(x >> 16);
}

#define GLOBAL_AS __attribute__((address_space(1)))
#define LDS_AS __attribute__((address_space(3)))
__device__ __forceinline__ void async_cp16(const void* g, void* l) {
    __builtin_amdgcn_global_load_lds((const GLOBAL_AS unsigned int*)g,
                                     (LDS_AS unsigned int*)l, 16, 0, 0);
}

// ===========================================================================
// Fused prep: degree histogram + x->bf16 conversion + 5 weight transposes.
// Block ranges: [0,3125) deg_count; [3125,9375) conv_x; [9375,10527) transposes.
// ===========================================================================
__device__ __forceinline__ void tr_one(
    const float* __restrict__ in, u16* __restrict__ out, int K, int N, int n)
{
    for (int k = threadIdx.x; k < K; k += 256) {
        float v = (n < N) ? in[(size_t)k * N + n] : 0.f;
        out[(size_t)n * K + k] = f2bf(v);
    }
}

__global__ __launch_bounds__(256) void prep_fused(
    const int* __restrict__ ei, int* __restrict__ deg,
    const float* __restrict__ x, u16* __restrict__ xb,
    const float* __restrict__ W1a, const float* __restrict__ W2a,
    const float* __restrict__ W1b, const float* __restrict__ W2b,
    const float* __restrict__ Wlin,
    u16* __restrict__ W1aT, u16* __restrict__ W2aT,
    u16* __restrict__ W1bT, u16* __restrict__ W2bT, u16* __restrict__ WlinT)
{
    int b = blockIdx.x;
    if (b < 3125) {
        int e = b * 256 + threadIdx.x;
        if (e < N_EDGES) atomicAdd(&deg[ei[N_EDGES + e]], 1);
    } else if (b < 9375) {
        int i = (b - 3125) * 256 + threadIdx.x;
        float4 v = ((const float4*)x)[i];
        ushort4 o;
        o.x = f2bf(v.x); o.y = f2bf(v.y); o.z = f2bf(v.z); o.w = f2bf(v.w);
        ((ushort4*)xb)[i] = o;
    } else {
        int t = b - 9375;
        if (t < 256)       tr_one(W1a, W1aT, IN_CH, HID, t);
        else if (t < 512)  tr_one(W2a, W2aT, HID, HID, t - 256);
        else if (t < 768)  tr_one(W1b, W1bT, HID, HID, t - 512);
        else if (t < 1024) tr_one(W2b, W2bT, HID, HID, t - 768);
        else               tr_one(Wlin, WlinT, 2 * HID, OUT_CH, t - 1024);
    }
}

// ===========================================================================
// Scan (3 small kernels) + dst-sharded CSR fill
// ===========================================================================
__global__ __launch_bounds__(256) void scan1(
    const int* __restrict__ deg, int* __restrict__ excl, int* __restrict__ partials)
{
    __shared__ int lds[256];
    const int tid = threadIdx.x;
    const int base = blockIdx.x * 1024 + tid * 4;
    int v[4]; int s = 0;
#pragma unroll
    for (int i = 0; i < 4; i++) {
        int idx = base + i;
        v[i] = (idx < N_NODES) ? deg[idx] : 0;
        s += v[i];
    }
    lds[tid] = s;
    __syncthreads();
    for (int off = 1; off < 256; off <<= 1) {
        int t = (tid >= off) ? lds[tid - off] : 0;
        __syncthreads();
        lds[tid] += t;
        __syncthreads();
    }
    int run = lds[tid] - s;
#pragma unroll
    for (int i = 0; i < 4; i++) {
        int idx = base + i;
        if (idx < N_NODES) excl[idx] = run;
        run += v[i];
    }
    if (tid == 255) partials[blockIdx.x] = lds[255];
}

__global__ __launch_bounds__(64) void scan2(int* __restrict__ partials, int n)
{
    int l = threadIdx.x;
    int orig = (l < n) ? partials[l] : 0;
    int v = orig;
#pragma unroll
    for (int off = 1; off < 64; off <<= 1) {
        int t = __shfl_up(v, off, 64);
        if (l >= off) v += t;
    }
    if (l < n) partials[l] = v - orig;
}

__global__ __launch_bounds__(256) void scan3(
    int* __restrict__ excl, const int* __restrict__ partials, int* __restrict__ cursor)
{
    int idx = blockIdx.x * 256 + threadIdx.x;
    if (idx < N_NODES) {
        int r = excl[idx] + partials[idx >> 10];
        excl[idx] = r;
        cursor[idx] = r;
    }
}

// Dst-sharded fill: group g = blockIdx&7 handles dst in [g*6250,(g+1)*6250),
// so each group's csr stores land in one contiguous ~200 KB region (owned by
// one XCD's L2 -> write-combined) instead of 800k cross-XCD 64 B sectors.
// Each group streams the full edge list coalesced (8 x 6.4 MB total reads).
__global__ __launch_bounds__(256) void csr_fill(
    const int* __restrict__ ei, int* __restrict__ cursor, u16* __restrict__ csr_src)
{
    const int g = blockIdx.x & 7;
    const int c = blockIdx.x >> 3;
    const int lo = g * 6250, hi = lo + 6250;
    const int base = c * 2048;
#pragma unroll
    for (int i = 0; i < 8; i++) {
        int e = base + i * 256 + threadIdx.x;
        if (e < N_EDGES) {
            int s = ei[e];                 // unconditional: keep reads coalesced
            int d = ei[N_EDGES + e];
            if (d >= lo && d < hi) {
                int pos = atomicAdd(&cursor[d], 1);
                csr_src[pos] = (u16)s;
            }
        }
    }
}

// ===========================================================================
// Gather aggregation (R4 form: full row per wave, 4-deep unroll, bf16 I/O,
// fp32 accumulate): out[n] = feat[n] + sum_{e in row n} feat[src[e]]
// ===========================================================================
__global__ __launch_bounds__(256) void gather_agg_bf128(
    const u16* __restrict__ feat, const int* __restrict__ row_ptr,
    const int* __restrict__ row_end, const u16* __restrict__ csr_src,
    u16* __restrict__ out)
{
    int node = (blockIdx.x * 256 + threadIdx.x) >> 6;
    int lane = threadIdx.x & 63;
    if (node >= N_NODES) return;
    ushort2 sv = ((const ushort2*)(feat + (size_t)node * IN_CH))[lane];
    float ax = bf2f(sv.x), ay = bf2f(sv.y);
    int j = row_ptr[node], e = row_end[node];
    for (; j + 4 <= e; j += 4) {
        int s0 = csr_src[j], s1 = csr_src[j + 1];
        int s2 = csr_src[j + 2], s3 = csr_src[j + 3];
        ushort2 v0 = ((const ushort2*)(feat + (size_t)s0 * IN_CH))[lane];
        ushort2 v1 = ((const ushort2*)(feat + (size_t)s1 * IN_CH))[lane];
        ushort2 v2 = ((const ushort2*)(feat + (size_t)s2 * IN_CH))[lane];
        ushort2 v3 = ((const ushort2*)(feat + (size_t)s3 * IN_CH))[lane];
        ax += (bf2f(v0.x) + bf2f(v1.x)) + (bf2f(v2.x) + bf2f(v3.x));
        ay += (bf2f(v0.y) + bf2f(v1.y)) + (bf2f(v2.y) + bf2f(v3.y));
    }
    for (; j < e; j++) {
        int sa = csr_src[j];
        ushort2 va = ((const ushort2*)(feat + (size_t)sa * IN_CH))[lane];
        ax += bf2f(va.x); ay += bf2f(va.y);
    }
    ushort2 o; o.x = f2bf(ax); o.y = f2bf(ay);
    ((ushort2*)(out + (size_t)node * IN_CH))[lane] = o;
}

__global__ __launch_bounds__(256) void gather_agg_bf256(
    const u16* __restrict__ feat, const int* __restrict__ row_ptr,
    const int* __restrict__ row_end, const u16* __restrict__ csr_src,
    u16* __restrict__ out)
{
    int node = (blockIdx.x * 256 + threadIdx.x) >> 6;
    int lane = threadIdx.x & 63;
    if (node >= N_NODES) return;
    ushort4 sv = ((const ushort4*)(feat + (size_t)node * HID))[lane];
    float ax = bf2f(sv.x), ay = bf2f(sv.y), az = bf2f(sv.z), aw = bf2f(sv.w);
    int j = row_ptr[node], e = row_end[node];
    for (; j + 4 <= e; j += 4) {
        int s0 = csr_src[j], s1 = csr_src[j + 1];
        int s2 = csr_src[j + 2], s3 = csr_src[j + 3];
        ushort4 v0 = ((const ushort4*)(feat + (size_t)s0 * HID))[lane];
        ushort4 v1 = ((const ushort4*)(feat + (size_t)s1 * HID))[lane];
        ushort4 v2 = ((const ushort4*)(feat + (size_t)s2 * HID))[lane];
        ushort4 v3 = ((const ushort4*)(feat + (size_t)s3 * HID))[lane];
        ax += (bf2f(v0.x) + bf2f(v1.x)) + (bf2f(v2.x) + bf2f(v3.x));
        ay += (bf2f(v0.y) + bf2f(v1.y)) + (bf2f(v2.y) + bf2f(v3.y));
        az += (bf2f(v0.z) + bf2f(v1.z)) + (bf2f(v2.z) + bf2f(v3.z));
        aw += (bf2f(v0.w) + bf2f(v1.w)) + (bf2f(v2.w) + bf2f(v3.w));
    }
    for (; j < e; j++) {
        int sa = csr_src[j];
        ushort4 va = ((const ushort4*)(feat + (size_t)sa * HID))[lane];
        ax += bf2f(va.x); ay += bf2f(va.y); az += bf2f(va.z); aw += bf2f(va.w);
    }
    ushort4 o;
    o.x = f2bf(ax); o.y = f2bf(ay); o.z = f2bf(az); o.w = f2bf(aw);
    ((ushort4*)(out + (size_t)node * HID))[lane] = o;
}

// ===========================================================================
// bf16 MFMA GEMM, BK=64 (half the barrier drains of BK=32; 32 KB LDS keeps
// 2 blocks/CU): out = act(Aeff[M,K] @ BT^T + bias). Layout comments as before.
// ===========================================================================
__global__ __launch_bounds__(256, 2) void gemm_mfma(
    const u16* __restrict__ A, const u16* __restrict__ Acat, int Ksplit, int ldA,
    const u16* __restrict__ BT, const float* __restrict__ bias,
    void* __restrict__ out, int M, int Nreal, int K, int relu, int ldOut,
    int fuseLS)
{
    __shared__ u16 As[128 * 64];   // [row][k], 128 B rows
    __shared__ u16 Bs[128 * 64];

    const int tid = threadIdx.x;
    const int lane = tid & 63;
    const int wid = tid >> 6;
    const int wm = wid >> 1, wn = wid & 1;
    const int row0 = blockIdx.y * 128;
    const int col0 = blockIdx.x * 128;

    f32x4 acc[4][4];
#pragma unroll
    for (int i = 0; i < 4; i++)
#pragma unroll
        for (int j = 0; j < 4; j++) acc[i][j] = (f32x4){0.f, 0.f, 0.f, 0.f};

    for (int kk = 0; kk < K; kk += 64) {
        const u16* Abase = (Acat != nullptr && kk >= Ksplit) ? Acat : A;
        const int kbase = (Acat != nullptr && kk >= Ksplit) ? (kk - Ksplit) : kk;
        // stage A tile: 128 rows x 64 k = 1024 16B-chunks (4 per thread)
#pragma unroll
        for (int i = 0; i < 4; i++) {
            int chunk = i * 256 + tid;
            int r = chunk >> 3, c = chunk & 7;
            int grow = row0 + r; if (grow > M - 1) grow = M - 1;
            async_cp16(Abase + (size_t)grow * ldA + kbase + c * 8, As + chunk * 8);
        }
#pragma unroll
        for (int i = 0; i < 4; i++) {
            int chunk = i * 256 + tid;
            int r = chunk >> 3, c = chunk & 7;
            async_cp16(BT + (size_t)(col0 + r) * K + kk + c * 8, Bs + chunk * 8);
        }
        __syncthreads();

        const int koff = (lane >> 4) * 8;
        const int am = wm * 64 + (lane & 15);
        const int bn = wn * 64 + (lane & 15);
#pragma unroll
        for (int kc = 0; kc < 2; kc++) {
            bf16x8 af[4], bfr[4];
#pragma unroll
            for (int t = 0; t < 4; t++) {
                af[t]  = *(const bf16x8*)(As + (am + t * 16) * 64 + kc * 32 + koff);
                bfr[t] = *(const bf16x8*)(Bs + (bn + t * 16) * 64 + kc * 32 + koff);
            }
#pragma unroll
            for (int mt = 0; mt < 4; mt++)
#pragma unroll
                for (int nt = 0; nt < 4; nt++)
                    acc[mt][nt] = __builtin_amdgcn_mfma_f32_16x16x32_bf16(
                        af[mt], bfr[nt], acc[mt][nt], 0, 0, 0);
        }
        __syncthreads();
    }

    if (fuseLS) {
        if (wn != 0) return;
        const int quad = lane >> 4, li = lane & 15;
        float b0 = bias[li];
        float b1 = bias[16 + li];
        float b2 = (li < 8) ? bias[32 + li] : 0.f;
        float* o = (float*)out;
#pragma unroll
        for (int mt = 0; mt < 4; mt++) {
#pragma unroll
            for (int reg = 0; reg < 4; reg++) {
                int row = row0 + wm * 64 + mt * 16 + quad * 4 + reg;
                float v0 = acc[mt][0][reg] + b0;
                float v1 = acc[mt][1][reg] + b1;
                float v2 = (li < 8) ? (acc[mt][2][reg] + b2) : -INFINITY;
                float m = fmaxf(fmaxf(v0, v1), v2);
#pragma unroll
                for (int off = 1; off < 16; off <<= 1)
                    m = fmaxf(m, __shfl_xor(m, off, 64));
                float s = expf(v0 - m) + expf(v1 - m)
                        + ((li < 8) ? expf(v2 - m) : 0.f);
#pragma unroll
                for (int off = 1; off < 16; off <<= 1)
                    s += __shfl_xor(s, off, 64);
                float lg = m + logf(s);
                if (row < M) {
                    o[(size_t)row * OUT_CH + li] = v0 - lg;
                    o[(size_t)row * OUT_CH + 16 + li] = v1 - lg;
                    if (li < 8) o[(size_t)row * OUT_CH + 32 + li] = v2 - lg;
                }
            }
        }
        return;
    }

#pragma unroll
    for (int nt = 0; nt < 4; nt++) {
        int col = col0 + wn * 64 + nt * 16 + (lane & 15);
        bool colOk = (col < Nreal);
        float bv = colOk ? bias[col] : 0.f;
#pragma unroll
        for (int mt = 0; mt < 4; mt++) {
            int rbase = row0 + wm * 64 + mt * 16 + ((lane >> 4) << 2);
#pragma unroll
            for (int reg = 0; reg < 4; reg++) {
                int row = rbase + reg;
                if (colOk && row < M) {
                    float v = acc[mt][nt][reg] + bv;
                    if (relu) v = fmaxf(v, 0.f);
                    ((u16*)out)[(size_t)row * ldOut + col] = f2bf(v);
                }
            }
        }
    }
}

// ---------------------------------------------------------------------------
extern "C" void kernel_launch(void* const* d_in, const int* in_sizes, int n_in,
                              void* d_out, int out_size, void* d_ws, size_t ws_size,
                              hipStream_t stream)
{
    const float* x    = (const float*)d_in[0];
    const int*   ei   = (const int*)d_in[1];
    const float* W1a  = (const float*)d_in[2];
    const float* b1a  = (const float*)d_in[3];
    const float* W2a  = (const float*)d_in[4];
    const float* b2a  = (const float*)d_in[5];
    const float* W1b  = (const float*)d_in[6];
    const float* b1b  = (const float*)d_in[7];
    const float* W2b  = (const float*)d_in[8];
    const float* b2b  = (const float*)d_in[9];
    const float* Wlin = (const float*)d_in[10];
    const float* blin = (const float*)d_in[11];
    float* out = (float*)d_out;

    // ---- workspace carve-up (regions of 50000*256 bf16 = 25.6 MB) ----
    const size_t R = (size_t)N_NODES * HID;
    u16* R0 = (u16*)d_ws;          // xbf -> t2
    u16* R1 = R0 + R;              // zA
    u16* R2 = R1 + R;              // t1 -> h2
    u16* R3 = R2 + R;              // h1 (live to end)
    u16* R4 = R3 + R;              // zB
    u16* xbf = R0;
    u16* zA  = R1;
    u16* t1  = R2;
    u16* h1  = R3;
    u16* zB  = R4;
    u16* t2  = R0;
    u16* h2  = R2;

    u16* wts = R4 + R;
    u16* W1aT = wts;                       // [256,128]
    u16* W2aT = W1aT + 256 * 128;          // [256,256]
    u16* W1bT = W2aT + 256 * 256;
    u16* W2bT = W1bT + 256 * 256;
    u16* WlinT = W2bT + 256 * 256;         // [128,512] (rows 40..127 zero)
    int* deg    = (int*)(WlinT + 128 * 512);
    int* rowp   = deg + N_NODES;
    int* cursor = rowp + N_NODES;
    int* part   = cursor + N_NODES;
    u16* csr    = (u16*)(part + 64);       // [N_EDGES] u16 src ids

    dim3 blk(256);
    const int scanBlocks = (N_NODES + 1023) / 1024;  // 49
    const int aggBlocks  = (N_NODES + 3) / 4;        // 12500
    const int fillBlocks = 8 * ((N_EDGES + 2047) / 2048);  // 8 dst-groups
    dim3 g2(2, (N_NODES + 127) / 128);
    dim3 g1(1, (N_NODES + 127) / 128);

    // ---- prep: histogram + conversions (fused) ----
    hipMemsetAsync(deg, 0, N_NODES * sizeof(int), stream);
    prep_fused<<<10527, blk, 0, stream>>>(ei, deg, x, xbf,
                                          W1a, W2a, W1b, W2b, Wlin,
                                          W1aT, W2aT, W1bT, W2bT, WlinT);
    scan1<<<scanBlocks, blk, 0, stream>>>(deg, rowp, part);
    scan2<<<1, 64, 0, stream>>>(part, scanBlocks);
    scan3<<<(N_NODES + 255) / 256, blk, 0, stream>>>(rowp, part, cursor);
    csr_fill<<<fillBlocks, blk, 0, stream>>>(ei, cursor, csr);

    // ---- Layer a ----
    gather_agg_bf128<<<aggBlocks, blk, 0, stream>>>(xbf, rowp, cursor, csr, zA);
    gemm_mfma<<<g2, blk, 0, stream>>>(zA, nullptr, 0, IN_CH, W1aT, b1a,
                                      t1, N_NODES, HID, IN_CH, 1, HID, 0);
    gemm_mfma<<<g2, blk, 0, stream>>>(t1, nullptr, 0, HID, W2aT, b2a,
                                      h1, N_NODES, HID, HID, 1, HID, 0);

    // ---- Layer b ----
    gather_agg_bf256<<<aggBlocks, blk, 0, stream>>>(h1, rowp, cursor, csr, zB);
    gemm_mfma<<<g2, blk, 0, stream>>>(zB, nullptr, 0, HID, W1bT, b1b,
                                      t2, N_NODES, HID, HID, 1, HID, 0);
    gemm_mfma<<<g2, blk, 0, stream>>>(t2, nullptr, 0, HID, W2bT, b2b,
                                      h2, N_NODES, HID, HID, 1, HID, 0);

    // ---- Final linear on [h1 | h2] + fused log_softmax -> d_out ----
    gemm_mfma<<<g1, blk, 0, stream>>>(h1, h2, HID, HID, WlinT, blin,
                                      out, N_NODES, OUT_CH, 2 * HID, 0, OUT_CH, 1);
}

// Round 7
// 383.938 us; speedup vs baseline: 1.5206x; 1.0796x over previous
//
#include <hip/hip_runtime.h>
#include <math.h>

// Problem constants
#define N_NODES 50000
#define N_EDGES 800000
#define IN_CH 128
#define HID 256
#define OUT_CH 40

typedef unsigned short u16;
typedef __attribute__((ext_vector_type(8))) short bf16x8;
typedef __attribute__((ext_vector_type(4))) float f32x4;

__device__ __forceinline__ float bf2f(u16 u) {
    union { unsigned int i; float f; } v; v.i = ((unsigned int)u) << 16; return v.f;
}
__device__ __forceinline__ u16 f2bf(float f) {   // round-to-nearest-even
    union { float f; unsigned int i; } v; v.f = f;
    unsigned int x = v.i;
    x += 0x7fffu + ((x >> 16) & 1u);
    return (u16)(x >> 16);
}

#define GLOBAL_AS __attribute__((address_space(1)))
#define LDS_AS __attribute__((address_space(3)))
__device__ __forceinline__ void async_cp16(const void* g, void* l) {
    __builtin_amdgcn_global_load_lds((const GLOBAL_AS unsigned int*)g,
                                     (LDS_AS unsigned int*)l, 16, 0, 0);
}

// ===========================================================================
// Fused prep: degree histogram + x->bf16 conversion + 5 weight transposes.
// Block ranges: [0,3125) deg_count; [3125,9375) conv_x; [9375,10527) transposes.
// ===========================================================================
__device__ __forceinline__ void tr_one(
    const float* __restrict__ in, u16* __restrict__ out, int K, int N, int n)
{
    for (int k = threadIdx.x; k < K; k += 256) {
        float v = (n < N) ? in[(size_t)k * N + n] : 0.f;
        out[(size_t)n * K + k] = f2bf(v);
    }
}

__global__ __launch_bounds__(256) void prep_fused(
    const int* __restrict__ ei, int* __restrict__ deg,
    const float* __restrict__ x, u16* __restrict__ xb,
    const float* __restrict__ W1a, const float* __restrict__ W2a,
    const float* __restrict__ W1b, const float* __restrict__ W2b,
    const float* __restrict__ Wlin,
    u16* __restrict__ W1aT, u16* __restrict__ W2aT,
    u16* __restrict__ W1bT, u16* __restrict__ W2bT, u16* __restrict__ WlinT)
{
    int b = blockIdx.x;
    if (b < 3125) {
        int e = b * 256 + threadIdx.x;
        if (e < N_EDGES) atomicAdd(&deg[ei[N_EDGES + e]], 1);
    } else if (b < 9375) {
        int i = (b - 3125) * 256 + threadIdx.x;
        float4 v = ((const float4*)x)[i];
        ushort4 o;
        o.x = f2bf(v.x); o.y = f2bf(v.y); o.z = f2bf(v.z); o.w = f2bf(v.w);
        ((ushort4*)xb)[i] = o;
    } else {
        int t = b - 9375;
        if (t < 256)       tr_one(W1a, W1aT, IN_CH, HID, t);
        else if (t < 512)  tr_one(W2a, W2aT, HID, HID, t - 256);
        else if (t < 768)  tr_one(W1b, W1bT, HID, HID, t - 512);
        else if (t < 1024) tr_one(W2b, W2bT, HID, HID, t - 768);
        else               tr_one(Wlin, WlinT, 2 * HID, OUT_CH, t - 1024);
    }
}

// ===========================================================================
// Scan (2 kernels) + dst-sharded CSR fill
// ===========================================================================
__global__ __launch_bounds__(256) void scan1(
    const int* __restrict__ deg, int* __restrict__ excl, int* __restrict__ partials)
{
    __shared__ int lds[256];
    const int tid = threadIdx.x;
    const int base = blockIdx.x * 1024 + tid * 4;
    int v[4]; int s = 0;
#pragma unroll
    for (int i = 0; i < 4; i++) {
        int idx = base + i;
        v[i] = (idx < N_NODES) ? deg[idx] : 0;
        s += v[i];
    }
    lds[tid] = s;
    __syncthreads();
    for (int off = 1; off < 256; off <<= 1) {
        int t = (tid >= off) ? lds[tid - off] : 0;
        __syncthreads();
        lds[tid] += t;
        __syncthreads();
    }
    int run = lds[tid] - s;
#pragma unroll
    for (int i = 0; i < 4; i++) {
        int idx = base + i;
        if (idx < N_NODES) excl[idx] = run;
        run += v[i];
    }
    if (tid == 255) partials[blockIdx.x] = lds[255];
}

// scan3: each block wave-scans the 49 block partials itself (no scan2 launch),
// then adds the offset; writes row_ptr (excl) and cursor copy.
__global__ __launch_bounds__(256) void scan3(
    int* __restrict__ excl, const int* __restrict__ partials,
    int* __restrict__ cursor, int nPart)
{
    __shared__ int bp[64];
    const int tid = threadIdx.x;
    if (tid < 64) {
        int orig = (tid < nPart) ? partials[tid] : 0;
        int v = orig;
#pragma unroll
        for (int off = 1; off < 64; off <<= 1) {
            int t = __shfl_up(v, off, 64);
            if (tid >= off) v += t;
        }
        bp[tid] = v - orig;   // exclusive prefix
    }
    __syncthreads();
    int idx = blockIdx.x * 256 + tid;
    if (idx < N_NODES) {
        int r = excl[idx] + bp[idx >> 10];
        excl[idx] = r;
        cursor[idx] = r;
    }
}

// Dst-sharded fill: group g = blockIdx&7 handles dst in [g*6250,(g+1)*6250),
// so each group's csr stores land in one contiguous ~200 KB region instead of
// 800k cross-XCD 64 B sectors. Each group streams the edge list coalesced.
__global__ __launch_bounds__(256) void csr_fill(
    const int* __restrict__ ei, int* __restrict__ cursor, u16* __restrict__ csr_src)
{
    const int g = blockIdx.x & 7;
    const int c = blockIdx.x >> 3;
    const int lo = g * 6250, hi = lo + 6250;
    const int base = c * 2048;
#pragma unroll
    for (int i = 0; i < 8; i++) {
        int e = base + i * 256 + threadIdx.x;
        if (e < N_EDGES) {
            int s = ei[e];                 // unconditional: keep reads coalesced
            int d = ei[N_EDGES + e];
            if (d >= lo && d < hi) {
                int pos = atomicAdd(&cursor[d], 1);
                csr_src[pos] = (u16)s;
            }
        }
    }
}

// ===========================================================================
// Gather aggregation (full row per wave, 4-deep unroll, bf16 I/O, fp32 acc):
//   out[n] = feat[n] + sum_{e in row n} feat[src[e]]
// ===========================================================================
__global__ __launch_bounds__(256) void gather_agg_bf128(
    const u16* __restrict__ feat, const int* __restrict__ row_ptr,
    const int* __restrict__ row_end, const u16* __restrict__ csr_src,
    u16* __restrict__ out)
{
    int node = (blockIdx.x * 256 + threadIdx.x) >> 6;
    int lane = threadIdx.x & 63;
    if (node >= N_NODES) return;
    ushort2 sv = ((const ushort2*)(feat + (size_t)node * IN_CH))[lane];
    float ax = bf2f(sv.x), ay = bf2f(sv.y);
    int j = row_ptr[node], e = row_end[node];
    for (; j + 4 <= e; j += 4) {
        int s0 = csr_src[j], s1 = csr_src[j + 1];
        int s2 = csr_src[j + 2], s3 = csr_src[j + 3];
        ushort2 v0 = ((const ushort2*)(feat + (size_t)s0 * IN_CH))[lane];
        ushort2 v1 = ((const ushort2*)(feat + (size_t)s1 * IN_CH))[lane];
        ushort2 v2 = ((const ushort2*)(feat + (size_t)s2 * IN_CH))[lane];
        ushort2 v3 = ((const ushort2*)(feat + (size_t)s3 * IN_CH))[lane];
        ax += (bf2f(v0.x) + bf2f(v1.x)) + (bf2f(v2.x) + bf2f(v3.x));
        ay += (bf2f(v0.y) + bf2f(v1.y)) + (bf2f(v2.y) + bf2f(v3.y));
    }
    for (; j < e; j++) {
        int sa = csr_src[j];
        ushort2 va = ((const ushort2*)(feat + (size_t)sa * IN_CH))[lane];
        ax += bf2f(va.x); ay += bf2f(va.y);
    }
    ushort2 o; o.x = f2bf(ax); o.y = f2bf(ay);
    ((ushort2*)(out + (size_t)node * IN_CH))[lane] = o;
}

__global__ __launch_bounds__(256) void gather_agg_bf256(
    const u16* __restrict__ feat, const int* __restrict__ row_ptr,
    const int* __restrict__ row_end, const u16* __restrict__ csr_src,
    u16* __restrict__ out)
{
    int node = (blockIdx.x * 256 + threadIdx.x) >> 6;
    int lane = threadIdx.x & 63;
    if (node >= N_NODES) return;
    ushort4 sv = ((const ushort4*)(feat + (size_t)node * HID))[lane];
    float ax = bf2f(sv.x), ay = bf2f(sv.y), az = bf2f(sv.z), aw = bf2f(sv.w);
    int j = row_ptr[node], e = row_end[node];
    for (; j + 4 <= e; j += 4) {
        int s0 = csr_src[j], s1 = csr_src[j + 1];
        int s2 = csr_src[j + 2], s3 = csr_src[j + 3];
        ushort4 v0 = ((const ushort4*)(feat + (size_t)s0 * HID))[lane];
        ushort4 v1 = ((const ushort4*)(feat + (size_t)s1 * HID))[lane];
        ushort4 v2 = ((const ushort4*)(feat + (size_t)s2 * HID))[lane];
        ushort4 v3 = ((const ushort4*)(feat + (size_t)s3 * HID))[lane];
        ax += (bf2f(v0.x) + bf2f(v1.x)) + (bf2f(v2.x) + bf2f(v3.x));
        ay += (bf2f(v0.y) + bf2f(v1.y)) + (bf2f(v2.y) + bf2f(v3.y));
        az += (bf2f(v0.z) + bf2f(v1.z)) + (bf2f(v2.z) + bf2f(v3.z));
        aw += (bf2f(v0.w) + bf2f(v1.w)) + (bf2f(v2.w) + bf2f(v3.w));
    }
    for (; j < e; j++) {
        int sa = csr_src[j];
        ushort4 va = ((const ushort4*)(feat + (size_t)sa * HID))[lane];
        ax += bf2f(va.x); ay += bf2f(va.y); az += bf2f(va.z); aw += bf2f(va.w);
    }
    ushort4 o;
    o.x = f2bf(ax); o.y = f2bf(ay); o.z = f2bf(az); o.w = f2bf(aw);
    ((ushort4*)(out + (size_t)node * HID))[lane] = o;
}

// ===========================================================================
// bf16 MFMA GEMM (m97 structure, BK=32 — known-good R4 codegen):
//   out = act(Aeff[M,K] @ BT^T + bias)
// __launch_bounds__(256,3): >=3 blocks/CU resident (grid 782 ~ 768 co-resident)
// ===========================================================================
__global__ __launch_bounds__(256, 3) void gemm_mfma(
    const u16* __restrict__ A, const u16* __restrict__ Acat, int Ksplit, int ldA,
    const u16* __restrict__ BT, const float* __restrict__ bias,
    void* __restrict__ out, int M, int Nreal, int K, int relu, int ldOut,
    int fuseLS)
{
    __shared__ u16 As[128 * 32];
    __shared__ u16 Bs[128 * 32];

    const int tid = threadIdx.x;
    const int lane = tid & 63;
    const int wid = tid >> 6;
    const int wm = wid >> 1, wn = wid & 1;
    const int row0 = blockIdx.y * 128;
    const int col0 = blockIdx.x * 128;

    f32x4 acc[4][4];
#pragma unroll
    for (int i = 0; i < 4; i++)
#pragma unroll
        for (int j = 0; j < 4; j++) acc[i][j] = (f32x4){0.f, 0.f, 0.f, 0.f};

    for (int kk = 0; kk < K; kk += 32) {
        const u16* Abase = (Acat != nullptr && kk >= Ksplit) ? Acat : A;
        const int kbase = (Acat != nullptr && kk >= Ksplit) ? (kk - Ksplit) : kk;
#pragma unroll
        for (int i = 0; i < 2; i++) {
            int chunk = i * 256 + tid;
            int r = chunk >> 2, c = chunk & 3;
            int grow = row0 + r; if (grow > M - 1) grow = M - 1;
            async_cp16(Abase + (size_t)grow * ldA + kbase + c * 8, As + chunk * 8);
        }
#pragma unroll
        for (int i = 0; i < 2; i++) {
            int chunk = i * 256 + tid;
            int r = chunk >> 2, c = chunk & 3;
            async_cp16(BT + (size_t)(col0 + r) * K + kk + c * 8, Bs + chunk * 8);
        }
        __syncthreads();

        const int koff = (lane >> 4) * 8;
        const int am = wm * 64 + (lane & 15);
        const int bn = wn * 64 + (lane & 15);
        bf16x8 af[4], bfr[4];
#pragma unroll
        for (int t = 0; t < 4; t++) {
            af[t]  = *(const bf16x8*)(As + (am + t * 16) * 32 + koff);
            bfr[t] = *(const bf16x8*)(Bs + (bn + t * 16) * 32 + koff);
        }
#pragma unroll
        for (int mt = 0; mt < 4; mt++)
#pragma unroll
            for (int nt = 0; nt < 4; nt++)
                acc[mt][nt] = __builtin_amdgcn_mfma_f32_16x16x32_bf16(
                    af[mt], bfr[nt], acc[mt][nt], 0, 0, 0);
        __syncthreads();
    }

    if (fuseLS) {
        if (wn != 0) return;
        const int quad = lane >> 4, li = lane & 15;
        float b0 = bias[li];
        float b1 = bias[16 + li];
        float b2 = (li < 8) ? bias[32 + li] : 0.f;
        float* o = (float*)out;
#pragma unroll
        for (int mt = 0; mt < 4; mt++) {
#pragma unroll
            for (int reg = 0; reg < 4; reg++) {
                int row = row0 + wm * 64 + mt * 16 + quad * 4 + reg;
                float v0 = acc[mt][0][reg] + b0;
                float v1 = acc[mt][1][reg] + b1;
                float v2 = (li < 8) ? (acc[mt][2][reg] + b2) : -INFINITY;
                float m = fmaxf(fmaxf(v0, v1), v2);
#pragma unroll
                for (int off = 1; off < 16; off <<= 1)
                    m = fmaxf(m, __shfl_xor(m, off, 64));
                float s = expf(v0 - m) + expf(v1 - m)
                        + ((li < 8) ? expf(v2 - m) : 0.f);
#pragma unroll
                for (int off = 1; off < 16; off <<= 1)
                    s += __shfl_xor(s, off, 64);
                float lg = m + logf(s);
                if (row < M) {
                    o[(size_t)row * OUT_CH + li] = v0 - lg;
                    o[(size_t)row * OUT_CH + 16 + li] = v1 - lg;
                    if (li < 8) o[(size_t)row * OUT_CH + 32 + li] = v2 - lg;
                }
            }
        }
        return;
    }

#pragma unroll
    for (int nt = 0; nt < 4; nt++) {
        int col = col0 + wn * 64 + nt * 16 + (lane & 15);
        bool colOk = (col < Nreal);
        float bv = colOk ? bias[col] : 0.f;
#pragma unroll
        for (int mt = 0; mt < 4; mt++) {
            int rbase = row0 + wm * 64 + mt * 16 + ((lane >> 4) << 2);
#pragma unroll
            for (int reg = 0; reg < 4; reg++) {
                int row = rbase + reg;
                if (colOk && row < M) {
                    float v = acc[mt][nt][reg] + bv;
                    if (relu) v = fmaxf(v, 0.f);
                    ((u16*)out)[(size_t)row * ldOut + col] = f2bf(v);
                }
            }
        }
    }
}

// ---------------------------------------------------------------------------
extern "C" void kernel_launch(void* const* d_in, const int* in_sizes, int n_in,
                              void* d_out, int out_size, void* d_ws, size_t ws_size,
                              hipStream_t stream)
{
    const float* x    = (const float*)d_in[0];
    const int*   ei   = (const int*)d_in[1];
    const float* W1a  = (const float*)d_in[2];
    const float* b1a  = (const float*)d_in[3];
    const float* W2a  = (const float*)d_in[4];
    const float* b2a  = (const float*)d_in[5];
    const float* W1b  = (const float*)d_in[6];
    const float* b1b  = (const float*)d_in[7];
    const float* W2b  = (const float*)d_in[8];
    const float* b2b  = (const float*)d_in[9];
    const float* Wlin = (const float*)d_in[10];
    const float* blin = (const float*)d_in[11];
    float* out = (float*)d_out;

    // ---- workspace carve-up (regions of 50000*256 bf16 = 25.6 MB) ----
    const size_t R = (size_t)N_NODES * HID;
    u16* R0 = (u16*)d_ws;          // xbf -> t2
    u16* R1 = R0 + R;              // zA
    u16* R2 = R1 + R;              // t1 -> h2
    u16* R3 = R2 + R;              // h1 (live to end)
    u16* R4 = R3 + R;              // zB
    u16* xbf = R0;
    u16* zA  = R1;
    u16* t1  = R2;
    u16* h1  = R3;
    u16* zB  = R4;
    u16* t2  = R0;
    u16* h2  = R2;

    u16* wts = R4 + R;
    u16* W1aT = wts;                       // [256,128]
    u16* W2aT = W1aT + 256 * 128;          // [256,256]
    u16* W1bT = W2aT + 256 * 256;
    u16* W2bT = W1bT + 256 * 256;
    u16* WlinT = W2bT + 256 * 256;         // [128,512] (rows 40..127 zero)
    int* deg    = (int*)(WlinT + 128 * 512);
    int* rowp   = deg + N_NODES;
    int* cursor = rowp + N_NODES;
    int* part   = cursor + N_NODES;
    u16* csr    = (u16*)(part + 64);       // [N_EDGES] u16 src ids

    dim3 blk(256);
    const int scanBlocks = (N_NODES + 1023) / 1024;  // 49
    const int aggBlocks  = (N_NODES + 3) / 4;        // 12500
    const int fillBlocks = 8 * ((N_EDGES + 2047) / 2048);  // 8 dst-groups
    dim3 g2(2, (N_NODES + 127) / 128);
    dim3 g1(1, (N_NODES + 127) / 128);

    // ---- prep: histogram + conversions (fused) ----
    hipMemsetAsync(deg, 0, N_NODES * sizeof(int), stream);
    prep_fused<<<10527, blk, 0, stream>>>(ei, deg, x, xbf,
                                          W1a, W2a, W1b, W2b, Wlin,
                                          W1aT, W2aT, W1bT, W2bT, WlinT);
    scan1<<<scanBlocks, blk, 0, stream>>>(deg, rowp, part);
    scan3<<<(N_NODES + 255) / 256, blk, 0, stream>>>(rowp, part, cursor, scanBlocks);
    csr_fill<<<fillBlocks, blk, 0, stream>>>(ei, cursor, csr);

    // ---- Layer a ----
    gather_agg_bf128<<<aggBlocks, blk, 0, stream>>>(xbf, rowp, cursor, csr, zA);
    gemm_mfma<<<g2, blk, 0, stream>>>(zA, nullptr, 0, IN_CH, W1aT, b1a,
                                      t1, N_NODES, HID, IN_CH, 1, HID, 0);
    gemm_mfma<<<g2, blk, 0, stream>>>(t1, nullptr, 0, HID, W2aT, b2a,
                                      h1, N_NODES, HID, HID, 1, HID, 0);

    // ---- Layer b ----
    gather_agg_bf256<<<aggBlocks, blk, 0, stream>>>(h1, rowp, cursor, csr, zB);
    gemm_mfma<<<g2, blk, 0, stream>>>(zB, nullptr, 0, HID, W1bT, b1b,
                                      t2, N_NODES, HID, HID, 1, HID, 0);
    gemm_mfma<<<g2, blk, 0, stream>>>(t2, nullptr, 0, HID, W2bT, b2b,
                                      h2, N_NODES, HID, HID, 1, HID, 0);

    // ---- Final linear on [h1 | h2] + fused log_softmax -> d_out ----
    gemm_mfma<<<g1, blk, 0, stream>>>(h1, h2, HID, HID, WlinT, blin,
                                      out, N_NODES, OUT_CH, 2 * HID, 0, OUT_CH, 1);
}

// Round 8
// 366.866 us; speedup vs baseline: 1.5914x; 1.0465x over previous
//
#include <hip/hip_runtime.h>
#include <math.h>

// Problem constants
#define N_NODES 50000
#define N_EDGES 800000
#define IN_CH 128
#define HID 256
#define OUT_CH 40

typedef unsigned short u16;
typedef unsigned char u8;
typedef __attribute__((ext_vector_type(8))) short bf16x8;
typedef __attribute__((ext_vector_type(4))) float f32x4;
typedef __attribute__((ext_vector_type(2))) float f32x2;

__device__ __forceinline__ float bf2f(u16 u) {
    union { unsigned int i; float f; } v; v.i = ((unsigned int)u) << 16; return v.f;
}
__device__ __forceinline__ u16 f2bf(float f) {   // round-to-nearest-even
    union { float f; unsigned int i; } v; v.f = f;
    unsigned int x = v.i;
    x += 0x7fffu + ((x >> 16) & 1u);
    return (u16)(x >> 16);
}

#define GLOBAL_AS __attribute__((address_space(1)))
#define LDS_AS __attribute__((address_space(3)))
__device__ __forceinline__ void async_cp16(const void* g, void* l) {
    __builtin_amdgcn_global_load_lds((const GLOBAL_AS unsigned int*)g,
                                     (LDS_AS unsigned int*)l, 16, 0, 0);
}

// ===========================================================================
// Fused prep: degree histogram + x->{bf16,fp8} conversion + weight transposes.
// Block ranges: [0,3125) deg_count; [3125,9375) conv_x; [9375,10527) transposes.
// ===========================================================================
__device__ __forceinline__ void tr_one(
    const float* __restrict__ in, u16* __restrict__ out, int K, int N, int n)
{
    for (int k = threadIdx.x; k < K; k += 256) {
        float v = (n < N) ? in[(size_t)k * N + n] : 0.f;
        out[(size_t)n * K + k] = f2bf(v);
    }
}

__global__ __launch_bounds__(256) void prep_fused(
    const int* __restrict__ ei, int* __restrict__ deg,
    const float* __restrict__ x, u16* __restrict__ xb, u8* __restrict__ xf8,
    const float* __restrict__ W1a, const float* __restrict__ W2a,
    const float* __restrict__ W1b, const float* __restrict__ W2b,
    const float* __restrict__ Wlin,
    u16* __restrict__ W1aT, u16* __restrict__ W2aT,
    u16* __restrict__ W1bT, u16* __restrict__ W2bT, u16* __restrict__ WlinT)
{
    int b = blockIdx.x;
    if (b < 3125) {
        int e = b * 256 + threadIdx.x;
        if (e < N_EDGES) atomicAdd(&deg[ei[N_EDGES + e]], 1);
    } else if (b < 9375) {
        int i = (b - 3125) * 256 + threadIdx.x;
        float4 v = ((const float4*)x)[i];
        ushort4 o;
        o.x = f2bf(v.x); o.y = f2bf(v.y); o.z = f2bf(v.z); o.w = f2bf(v.w);
        ((ushort4*)xb)[i] = o;
        int p = __builtin_amdgcn_cvt_pk_fp8_f32(v.x, v.y, 0, false);
        p = __builtin_amdgcn_cvt_pk_fp8_f32(v.z, v.w, p, true);
        ((unsigned int*)xf8)[i] = (unsigned int)p;
    } else {
        int t = b - 9375;
        if (t < 256)       tr_one(W1a, W1aT, IN_CH, HID, t);
        else if (t < 512)  tr_one(W2a, W2aT, HID, HID, t - 256);
        else if (t < 768)  tr_one(W1b, W1bT, HID, HID, t - 512);
        else if (t < 1024) tr_one(W2b, W2bT, HID, HID, t - 768);
        else               tr_one(Wlin, WlinT, 2 * HID, OUT_CH, t - 1024);
    }
}

// ===========================================================================
// Scan (2 kernels) + dst-sharded CSR fill
// ===========================================================================
__global__ __launch_bounds__(256) void scan1(
    const int* __restrict__ deg, int* __restrict__ excl, int* __restrict__ partials)
{
    __shared__ int lds[256];
    const int tid = threadIdx.x;
    const int base = blockIdx.x * 1024 + tid * 4;
    int v[4]; int s = 0;
#pragma unroll
    for (int i = 0; i < 4; i++) {
        int idx = base + i;
        v[i] = (idx < N_NODES) ? deg[idx] : 0;
        s += v[i];
    }
    lds[tid] = s;
    __syncthreads();
    for (int off = 1; off < 256; off <<= 1) {
        int t = (tid >= off) ? lds[tid - off] : 0;
        __syncthreads();
        lds[tid] += t;
        __syncthreads();
    }
    int run = lds[tid] - s;
#pragma unroll
    for (int i = 0; i < 4; i++) {
        int idx = base + i;
        if (idx < N_NODES) excl[idx] = run;
        run += v[i];
    }
    if (tid == 255) partials[blockIdx.x] = lds[255];
}

// scan3: each block wave-scans the 49 block partials itself, adds offsets.
__global__ __launch_bounds__(256) void scan3(
    int* __restrict__ excl, const int* __restrict__ partials,
    int* __restrict__ cursor, int nPart)
{
    __shared__ int bp[64];
    const int tid = threadIdx.x;
    if (tid < 64) {
        int orig = (tid < nPart) ? partials[tid] : 0;
        int v = orig;
#pragma unroll
        for (int off = 1; off < 64; off <<= 1) {
            int t = __shfl_up(v, off, 64);
            if (tid >= off) v += t;
        }
        bp[tid] = v - orig;
    }
    __syncthreads();
    int idx = blockIdx.x * 256 + tid;
    if (idx < N_NODES) {
        int r = excl[idx] + bp[idx >> 10];
        excl[idx] = r;
        cursor[idx] = r;
    }
}

// Dst-sharded fill: group g = blockIdx&7 handles dst in [g*6250,(g+1)*6250).
__global__ __launch_bounds__(256) void csr_fill(
    const int* __restrict__ ei, int* __restrict__ cursor, u16* __restrict__ csr_src)
{
    const int g = blockIdx.x & 7;
    const int c = blockIdx.x >> 3;
    const int lo = g * 6250, hi = lo + 6250;
    const int base = c * 2048;
#pragma unroll
    for (int i = 0; i < 8; i++) {
        int e = base + i * 256 + threadIdx.x;
        if (e < N_EDGES) {
            int s = ei[e];
            int d = ei[N_EDGES + e];
            if (d >= lo && d < hi) {
                int pos = atomicAdd(&cursor[d], 1);
                csr_src[pos] = (u16)s;
            }
        }
    }
}

// ===========================================================================
// Gather aggregation, fp8 neighbor table + bf16 self term, fp32 accumulate:
//   out[n] = feat_bf[n] + sum_{e in row n} fp8(feat[src[e]])
// One 64-lane wave per node; 4-deep unroll for MLP.
// ===========================================================================
__global__ __launch_bounds__(256) void gather_agg_f8_128(
    const u16* __restrict__ feat_bf, const u8* __restrict__ feat_f8,
    const int* __restrict__ row_ptr, const int* __restrict__ row_end,
    const u16* __restrict__ csr_src, u16* __restrict__ out)
{
    int node = (blockIdx.x * 256 + threadIdx.x) >> 6;
    int lane = threadIdx.x & 63;
    if (node >= N_NODES) return;
    ushort2 sv = ((const ushort2*)(feat_bf + (size_t)node * IN_CH))[lane];
    float ax = bf2f(sv.x), ay = bf2f(sv.y);
    int j = row_ptr[node], e = row_end[node];
    for (; j + 4 <= e; j += 4) {
        int s0 = csr_src[j], s1 = csr_src[j + 1];
        int s2 = csr_src[j + 2], s3 = csr_src[j + 3];
        int v0 = ((const u16*)(feat_f8 + (size_t)s0 * IN_CH))[lane];
        int v1 = ((const u16*)(feat_f8 + (size_t)s1 * IN_CH))[lane];
        int v2 = ((const u16*)(feat_f8 + (size_t)s2 * IN_CH))[lane];
        int v3 = ((const u16*)(feat_f8 + (size_t)s3 * IN_CH))[lane];
        f32x2 d0 = __builtin_amdgcn_cvt_pk_f32_fp8(v0, false);
        f32x2 d1 = __builtin_amdgcn_cvt_pk_f32_fp8(v1, false);
        f32x2 d2 = __builtin_amdgcn_cvt_pk_f32_fp8(v2, false);
        f32x2 d3 = __builtin_amdgcn_cvt_pk_f32_fp8(v3, false);
        ax += (d0.x + d1.x) + (d2.x + d3.x);
        ay += (d0.y + d1.y) + (d2.y + d3.y);
    }
    for (; j < e; j++) {
        int sa = csr_src[j];
        int va = ((const u16*)(feat_f8 + (size_t)sa * IN_CH))[lane];
        f32x2 da = __builtin_amdgcn_cvt_pk_f32_fp8(va, false);
        ax += da.x; ay += da.y;
    }
    ushort2 o; o.x = f2bf(ax); o.y = f2bf(ay);
    ((ushort2*)(out + (size_t)node * IN_CH))[lane] = o;
}

__global__ __launch_bounds__(256) void gather_agg_f8_256(
    const u16* __restrict__ feat_bf, const u8* __restrict__ feat_f8,
    const int* __restrict__ row_ptr, const int* __restrict__ row_end,
    const u16* __restrict__ csr_src, u16* __restrict__ out)
{
    int node = (blockIdx.x * 256 + threadIdx.x) >> 6;
    int lane = threadIdx.x & 63;
    if (node >= N_NODES) return;
    ushort4 sv = ((const ushort4*)(feat_bf + (size_t)node * HID))[lane];
    float ax = bf2f(sv.x), ay = bf2f(sv.y), az = bf2f(sv.z), aw = bf2f(sv.w);
    int j = row_ptr[node], e = row_end[node];
    for (; j + 4 <= e; j += 4) {
        int s0 = csr_src[j], s1 = csr_src[j + 1];
        int s2 = csr_src[j + 2], s3 = csr_src[j + 3];
        int v0 = ((const int*)(feat_f8 + (size_t)s0 * HID))[lane];
        int v1 = ((const int*)(feat_f8 + (size_t)s1 * HID))[lane];
        int v2 = ((const int*)(feat_f8 + (size_t)s2 * HID))[lane];
        int v3 = ((const int*)(feat_f8 + (size_t)s3 * HID))[lane];
        f32x2 l0 = __builtin_amdgcn_cvt_pk_f32_fp8(v0, false);
        f32x2 h0 = __builtin_amdgcn_cvt_pk_f32_fp8(v0, true);
        f32x2 l1 = __builtin_amdgcn_cvt_pk_f32_fp8(v1, false);
        f32x2 h1v = __builtin_amdgcn_cvt_pk_f32_fp8(v1, true);
        f32x2 l2 = __builtin_amdgcn_cvt_pk_f32_fp8(v2, false);
        f32x2 h2v = __builtin_amdgcn_cvt_pk_f32_fp8(v2, true);
        f32x2 l3 = __builtin_amdgcn_cvt_pk_f32_fp8(v3, false);
        f32x2 h3 = __builtin_amdgcn_cvt_pk_f32_fp8(v3, true);
        ax += (l0.x + l1.x) + (l2.x + l3.x);
        ay += (l0.y + l1.y) + (l2.y + l3.y);
        az += (h0.x + h1v.x) + (h2v.x + h3.x);
        aw += (h0.y + h1v.y) + (h2v.y + h3.y);
    }
    for (; j < e; j++) {
        int sa = csr_src[j];
        int va = ((const int*)(feat_f8 + (size_t)sa * HID))[lane];
        f32x2 la = __builtin_amdgcn_cvt_pk_f32_fp8(va, false);
        f32x2 ha = __builtin_amdgcn_cvt_pk_f32_fp8(va, true);
        ax += la.x; ay += la.y; az += ha.x; aw += ha.y;
    }
    ushort4 o;
    o.x = f2bf(ax); o.y = f2bf(ay); o.z = f2bf(az); o.w = f2bf(aw);
    ((ushort4*)(out + (size_t)node * HID))[lane] = o;
}

// ===========================================================================
// bf16 MFMA GEMM (m97 structure, BK=32): out = act(Aeff[M,K] @ BT^T + bias)
// outF8 != null: additionally store e4m3 copy (fp8 neighbor table for gather).
// ===========================================================================
__global__ __launch_bounds__(256, 3) void gemm_mfma(
    const u16* __restrict__ A, const u16* __restrict__ Acat, int Ksplit, int ldA,
    const u16* __restrict__ BT, const float* __restrict__ bias,
    void* __restrict__ out, u8* __restrict__ outF8,
    int M, int Nreal, int K, int relu, int ldOut, int fuseLS)
{
    __shared__ u16 As[128 * 32];
    __shared__ u16 Bs[128 * 32];

    const int tid = threadIdx.x;
    const int lane = tid & 63;
    const int wid = tid >> 6;
    const int wm = wid >> 1, wn = wid & 1;
    const int row0 = blockIdx.y * 128;
    const int col0 = blockIdx.x * 128;

    f32x4 acc[4][4];
#pragma unroll
    for (int i = 0; i < 4; i++)
#pragma unroll
        for (int j = 0; j < 4; j++) acc[i][j] = (f32x4){0.f, 0.f, 0.f, 0.f};

    for (int kk = 0; kk < K; kk += 32) {
        const u16* Abase = (Acat != nullptr && kk >= Ksplit) ? Acat : A;
        const int kbase = (Acat != nullptr && kk >= Ksplit) ? (kk - Ksplit) : kk;
#pragma unroll
        for (int i = 0; i < 2; i++) {
            int chunk = i * 256 + tid;
            int r = chunk >> 2, c = chunk & 3;
            int grow = row0 + r; if (grow > M - 1) grow = M - 1;
            async_cp16(Abase + (size_t)grow * ldA + kbase + c * 8, As + chunk * 8);
        }
#pragma unroll
        for (int i = 0; i < 2; i++) {
            int chunk = i * 256 + tid;
            int r = chunk >> 2, c = chunk & 3;
            async_cp16(BT + (size_t)(col0 + r) * K + kk + c * 8, Bs + chunk * 8);
        }
        __syncthreads();

        const int koff = (lane >> 4) * 8;
        const int am = wm * 64 + (lane & 15);
        const int bn = wn * 64 + (lane & 15);
        bf16x8 af[4], bfr[4];
#pragma unroll
        for (int t = 0; t < 4; t++) {
            af[t]  = *(const bf16x8*)(As + (am + t * 16) * 32 + koff);
            bfr[t] = *(const bf16x8*)(Bs + (bn + t * 16) * 32 + koff);
        }
#pragma unroll
        for (int mt = 0; mt < 4; mt++)
#pragma unroll
            for (int nt = 0; nt < 4; nt++)
                acc[mt][nt] = __builtin_amdgcn_mfma_f32_16x16x32_bf16(
                    af[mt], bfr[nt], acc[mt][nt], 0, 0, 0);
        __syncthreads();
    }

    if (fuseLS) {
        if (wn != 0) return;
        const int quad = lane >> 4, li = lane & 15;
        float b0 = bias[li];
        float b1 = bias[16 + li];
        float b2 = (li < 8) ? bias[32 + li] : 0.f;
        float* o = (float*)out;
#pragma unroll
        for (int mt = 0; mt < 4; mt++) {
#pragma unroll
            for (int reg = 0; reg < 4; reg++) {
                int row = row0 + wm * 64 + mt * 16 + quad * 4 + reg;
                float v0 = acc[mt][0][reg] + b0;
                float v1 = acc[mt][1][reg] + b1;
                float v2 = (li < 8) ? (acc[mt][2][reg] + b2) : -INFINITY;
                float m = fmaxf(fmaxf(v0, v1), v2);
#pragma unroll
                for (int off = 1; off < 16; off <<= 1)
                    m = fmaxf(m, __shfl_xor(m, off, 64));
                float s = expf(v0 - m) + expf(v1 - m)
                        + ((li < 8) ? expf(v2 - m) : 0.f);
#pragma unroll
                for (int off = 1; off < 16; off <<= 1)
                    s += __shfl_xor(s, off, 64);
                float lg = m + logf(s);
                if (row < M) {
                    o[(size_t)row * OUT_CH + li] = v0 - lg;
                    o[(size_t)row * OUT_CH + 16 + li] = v1 - lg;
                    if (li < 8) o[(size_t)row * OUT_CH + 32 + li] = v2 - lg;
                }
            }
        }
        return;
    }

#pragma unroll
    for (int nt = 0; nt < 4; nt++) {
        int col = col0 + wn * 64 + nt * 16 + (lane & 15);
        bool colOk = (col < Nreal);
        float bv = colOk ? bias[col] : 0.f;
#pragma unroll
        for (int mt = 0; mt < 4; mt++) {
            int rbase = row0 + wm * 64 + mt * 16 + ((lane >> 4) << 2);
#pragma unroll
            for (int reg = 0; reg < 4; reg++) {
                int row = rbase + reg;
                if (colOk && row < M) {
                    float v = acc[mt][nt][reg] + bv;
                    if (relu) v = fmaxf(v, 0.f);
                    ((u16*)out)[(size_t)row * ldOut + col] = f2bf(v);
                    if (outF8 != nullptr) {
                        int pk = __builtin_amdgcn_cvt_pk_fp8_f32(v, v, 0, false);
                        outF8[(size_t)row * ldOut + col] = (u8)(pk & 0xff);
                    }
                }
            }
        }
    }
}

// ---------------------------------------------------------------------------
extern "C" void kernel_launch(void* const* d_in, const int* in_sizes, int n_in,
                              void* d_out, int out_size, void* d_ws, size_t ws_size,
                              hipStream_t stream)
{
    const float* x    = (const float*)d_in[0];
    const int*   ei   = (const int*)d_in[1];
    const float* W1a  = (const float*)d_in[2];
    const float* b1a  = (const float*)d_in[3];
    const float* W2a  = (const float*)d_in[4];
    const float* b2a  = (const float*)d_in[5];
    const float* W1b  = (const float*)d_in[6];
    const float* b1b  = (const float*)d_in[7];
    const float* W2b  = (const float*)d_in[8];
    const float* b2b  = (const float*)d_in[9];
    const float* Wlin = (const float*)d_in[10];
    const float* blin = (const float*)d_in[11];
    float* out = (float*)d_out;

    // ---- workspace carve-up (regions of 50000*256 bf16 = 25.6 MB) ----
    const size_t R = (size_t)N_NODES * HID;
    u16* R0 = (u16*)d_ws;          // xbf (first half) -> t2
    u16* R1 = R0 + R;              // zA (first half) + xf8 (second half) -> h1f8
    u16* R2 = R1 + R;              // t1 -> h2
    u16* R3 = R2 + R;              // h1 (live to end)
    u16* R4 = R3 + R;              // zB
    u16* xbf = R0;
    u16* zA  = R1;                                   // [50000,128] bf16
    u8*  xf8 = (u8*)(R1 + (size_t)N_NODES * IN_CH);  // [50000,128] fp8 (2nd half)
    u8*  h1f8 = (u8*)R1;                             // [50000,256] fp8 (after zA dead)
    u16* t1  = R2;
    u16* h1  = R3;
    u16* zB  = R4;
    u16* t2  = R0;
    u16* h2  = R2;

    u16* wts = R4 + R;
    u16* W1aT = wts;                       // [256,128]
    u16* W2aT = W1aT + 256 * 128;          // [256,256]
    u16* W1bT = W2aT + 256 * 256;
    u16* W2bT = W1bT + 256 * 256;
    u16* WlinT = W2bT + 256 * 256;         // [128,512] (rows 40..127 zero)
    int* deg    = (int*)(WlinT + 128 * 512);
    int* rowp   = deg + N_NODES;
    int* cursor = rowp + N_NODES;
    int* part   = cursor + N_NODES;
    u16* csr    = (u16*)(part + 64);       // [N_EDGES] u16 src ids

    dim3 blk(256);
    const int scanBlocks = (N_NODES + 1023) / 1024;  // 49
    const int aggBlocks  = (N_NODES + 3) / 4;        // 12500
    const int fillBlocks = 8 * ((N_EDGES + 2047) / 2048);
    dim3 g2(2, (N_NODES + 127) / 128);
    dim3 g1(1, (N_NODES + 127) / 128);

    // ---- prep: histogram + conversions (fused) ----
    hipMemsetAsync(deg, 0, N_NODES * sizeof(int), stream);
    prep_fused<<<10527, blk, 0, stream>>>(ei, deg, x, xbf, xf8,
                                          W1a, W2a, W1b, W2b, Wlin,
                                          W1aT, W2aT, W1bT, W2bT, WlinT);
    scan1<<<scanBlocks, blk, 0, stream>>>(deg, rowp, part);
    scan3<<<(N_NODES + 255) / 256, blk, 0, stream>>>(rowp, part, cursor, scanBlocks);
    csr_fill<<<fillBlocks, blk, 0, stream>>>(ei, cursor, csr);

    // ---- Layer a ----
    gather_agg_f8_128<<<aggBlocks, blk, 0, stream>>>(xbf, xf8, rowp, cursor, csr, zA);
    gemm_mfma<<<g2, blk, 0, stream>>>(zA, nullptr, 0, IN_CH, W1aT, b1a,
                                      t1, nullptr, N_NODES, HID, IN_CH, 1, HID, 0);
    gemm_mfma<<<g2, blk, 0, stream>>>(t1, nullptr, 0, HID, W2aT, b2a,
                                      h1, h1f8, N_NODES, HID, HID, 1, HID, 0);

    // ---- Layer b ----
    gather_agg_f8_256<<<aggBlocks, blk, 0, stream>>>(h1, h1f8, rowp, cursor, csr, zB);
    gemm_mfma<<<g2, blk, 0, stream>>>(zB, nullptr, 0, HID, W1bT, b1b,
                                      t2, nullptr, N_NODES, HID, HID, 1, HID, 0);
    gemm_mfma<<<g2, blk, 0, stream>>>(t2, nullptr, 0, HID, W2bT, b2b,
                                      h2, nullptr, N_NODES, HID, HID, 1, HID, 0);

    // ---- Final linear on [h1 | h2] + fused log_softmax -> d_out ----
    gemm_mfma<<<g1, blk, 0, stream>>>(h1, h2, HID, HID, WlinT, blin,
                                      out, nullptr, N_NODES, OUT_CH, 2 * HID, 0, OUT_CH, 1);
}